// Round 2
// baseline (520.794 us; speedup 1.0000x reference)
//
#include <hip/hip_runtime.h>
#include <hip/hip_bf16.h>
#include <cstddef>

// GAT layer: B=8, N=2048, C_IN=128, C_OUT=64, fp32 in/out.
// Kernel A: h = inp@W (W in LDS), s1 = h@a1, s2 = h@a2. h stored as bf16.
// Kernel B: fused masked-softmax attention, one wave per (b,i) row,
//           online softmax over j-tiles of 64; acc[f] += p_j * h[b,j,f].
//
// WORKSPACE DISCIPLINE (round-1 lesson): total d_ws usage must stay small —
// 4.33 MB overflowed ws and trampled the harness's pristine input copies
// (first run passed, replays diverged). Now: 2 MB bf16 h + 128 KB s1/s2.

#define B_DIM 8
#define N_DIM 2048
#define C_IN 128
#define C_OUT 64
#define NROWS (B_DIM * N_DIM)   // 16384

__global__ __launch_bounds__(256) void gat_hproj(
    const float* __restrict__ inp,   // [B,N,C_IN]
    const float* __restrict__ W,     // [C_IN,C_OUT]
    const float* __restrict__ a,     // [2*C_OUT]
    __hip_bfloat16* __restrict__ hbf,// [B,N,C_OUT] bf16
    float* __restrict__ s1,          // [B,N]
    float* __restrict__ s2)          // [B,N]
{
    __shared__ float Wl[C_IN * C_OUT];   // 32 KB
    for (int t = threadIdx.x; t < C_IN * C_OUT; t += 256) Wl[t] = W[t];
    __syncthreads();

    const int wave = threadIdx.x >> 6;
    const int lane = threadIdx.x & 63;
    const int row  = blockIdx.x * 4 + wave;   // 0..NROWS-1

    const float* __restrict__ x = inp + (size_t)row * C_IN;
    float hv = 0.f;
#pragma unroll 8
    for (int c = 0; c < C_IN; ++c)
        hv = fmaf(x[c], Wl[c * C_OUT + lane], hv);   // x[c] is a wave-broadcast load

    hbf[(size_t)row * C_OUT + lane] = __float2bfloat16(hv);

    float p1 = hv * a[lane];
    float p2 = hv * a[C_OUT + lane];
#pragma unroll
    for (int off = 32; off; off >>= 1) {
        p1 += __shfl_xor(p1, off, 64);
        p2 += __shfl_xor(p2, off, 64);
    }
    if (lane == 0) { s1[row] = p1; s2[row] = p2; }
}

__global__ __launch_bounds__(256) void gat_attn(
    const float* __restrict__ adj,            // [N,N]
    const __hip_bfloat16* __restrict__ hbf,   // [B,N,C_OUT] bf16
    const float* __restrict__ s1,             // [B,N]
    const float* __restrict__ s2,             // [B,N]
    float* __restrict__ out)                  // [B,N,C_OUT]
{
    const int wave = threadIdx.x >> 6;
    const int lane = threadIdx.x & 63;
    const int row  = blockIdx.x * 4 + wave;   // 0..NROWS-1
    const int b = row >> 11;                  // N=2048
    const int i = row & (N_DIM - 1);

    const float s1i = s1[row];
    const __hip_bfloat16* __restrict__ hb = hbf + (size_t)b * N_DIM * C_OUT;
    const float* __restrict__ adjrow = adj + (size_t)i * N_DIM;
    const float* __restrict__ s2b    = s2  + (size_t)b * N_DIM;

    float m = -1e30f, l = 0.f, acc = 0.f;

    for (int j0 = 0; j0 < N_DIM; j0 += 64) {
        const int j = j0 + lane;
        // --- stats phase: lane = j ---
        const float av  = adjrow[j];
        const bool valid = (av > 0.f) || (j == i);   // adj + I > 0
        float e = s1i + s2b[j];
        e = (e > 0.f) ? e : 0.01f * e;               // leaky_relu
        float ee = valid ? e : -1e30f;

        float tmax = ee;
#pragma unroll
        for (int off = 32; off; off >>= 1)
            tmax = fmaxf(tmax, __shfl_xor(tmax, off, 64));

        const float newm = fmaxf(m, tmax);
        const float p = valid ? __expf(e - newm) : 0.f;   // masked -> exact 0

        float psum = p;
#pragma unroll
        for (int off = 32; off; off >>= 1)
            psum += __shfl_xor(psum, off, 64);

        const float scale = __expf(m - newm);   // ==1 when tile fully masked
        l = l * scale + psum;
        acc *= scale;

        // --- accumulate phase: lane = f ---
        const __hip_bfloat16* __restrict__ hj = hb + (size_t)j0 * C_OUT + lane;
#pragma unroll
        for (int jj = 0; jj < 64; ++jj) {
            const float pj = __shfl(p, jj, 64);
            acc = fmaf(pj, __bfloat162float(hj[(size_t)jj * C_OUT]), acc);
        }
        m = newm;
    }

    out[(size_t)row * C_OUT + lane] = acc / l;
}

extern "C" void kernel_launch(void* const* d_in, const int* in_sizes, int n_in,
                              void* d_out, int out_size, void* d_ws, size_t ws_size,
                              hipStream_t stream) {
    const float* inp = (const float*)d_in[0];   // [8,2048,128]
    const float* adj = (const float*)d_in[1];   // [2048,2048]
    const float* W   = (const float*)d_in[2];   // [128,64]
    const float* a   = (const float*)d_in[3];   // [128]
    float* out = (float*)d_out;                 // [8,2048,64]

    // ws layout (total 2.25 MB):
    //   [0, 2MB)      : h as bf16, NROWS*C_OUT ushorts
    //   [2MB, +64KB)  : s1 fp32
    //   [+64KB,+64KB) : s2 fp32
    __hip_bfloat16* hbf = (__hip_bfloat16*)d_ws;
    float* s1 = (float*)((char*)d_ws + (size_t)NROWS * C_OUT * sizeof(__hip_bfloat16));
    float* s2 = s1 + NROWS;

    gat_hproj<<<NROWS / 4, 256, 0, stream>>>(inp, W, a, hbf, s1, s2);
    gat_attn <<<NROWS / 4, 256, 0, stream>>>(adj, hbf, s1, s2, out);
}

// Round 3
// 155.401 us; speedup vs baseline: 3.3513x; 3.3513x over previous
//
#include <hip/hip_runtime.h>
#include <hip/hip_bf16.h>
#include <cstddef>
#include <cstdint>

// GAT layer: B=8, N=2048, C_IN=128, C_OUT=64, fp32 in/out.
//
// Rank-1 score structure: e[b,i,j] = lrelu(s1[b,i] + s2[b,j]); mask = adj>0 | diag.
// Masked entries contribute exp(-1e12 - m) == 0 exactly in fp32, so skipping them
// is bit-equivalent to the reference softmax.
//
// A: h = inp@W (W in LDS), writes hT bf16 [B][C_OUT][N] (LDS transpose), s1, s2.
// B: adj -> bitmask (ballot) + per-(b,i) softmax stats m_i, 1/l_i.
// C: P built DIRECTLY in MFMA A-fragment layout (P=exp(e-m)/l, bf16),
//    H as B-fragments (one b128 load each from hT), 16x16x32 bf16 MFMA,
//    16 i-rows/block, 4-way j-split across waves, LDS partial-sum epilogue.
//
// ws budget (round-1 lesson: stay well under 4 MB): 2MB hT + 128K s1/s2 +
// 512K mask + 128K stats = 2.75 MB.

#define B_DIM 8
#define N_DIM 2048
#define C_IN  128
#define C_OUT 64
#define NROWS (B_DIM * N_DIM)   // 16384

typedef short bf16x8 __attribute__((ext_vector_type(8)));
typedef float f32x4  __attribute__((ext_vector_type(4)));

static __device__ __forceinline__ short f2bf(float x) {
    __hip_bfloat16 b = __float2bfloat16(x);
    return *reinterpret_cast<short*>(&b);
}

// ---------------- Kernel A: projection + transpose + s1/s2 ----------------
__global__ __launch_bounds__(256) void gat_hproj(
    const float* __restrict__ inp,   // [B,N,C_IN]
    const float* __restrict__ W,     // [C_IN,C_OUT]
    const float* __restrict__ a,     // [2*C_OUT]
    __hip_bfloat16* __restrict__ hT, // [B][C_OUT][N] bf16
    float* __restrict__ s1,          // [B*N]
    float* __restrict__ s2)          // [B*N]
{
    __shared__ float Wl[C_IN * C_OUT];     // 32 KB
    __shared__ float a1l[C_OUT], a2l[C_OUT];
    __shared__ float tr[C_OUT][33];        // h block transposed: [f][row_local], +1 pad

    for (int t = threadIdx.x; t < C_IN * C_OUT; t += 256) Wl[t] = W[t];
    if (threadIdx.x < C_OUT) {
        a1l[threadIdx.x] = a[threadIdx.x];
        a2l[threadIdx.x] = a[C_OUT + threadIdx.x];
    }
    __syncthreads();

    const int wave = threadIdx.x >> 6;
    const int lane = threadIdx.x & 63;
    const int i0 = blockIdx.x * 32;        // 32 rows per block, never crosses batch
    const int b  = i0 >> 11;
    const int il = i0 & (N_DIM - 1);

    for (int g = 0; g < 2; ++g) {
        const int rl = wave * 8 + g * 4;   // local row base, 4 rows per group
        const size_t rbase = (size_t)(i0 + rl) * C_IN;
        const float* __restrict__ x0 = inp + rbase;
        const float* __restrict__ x1 = x0 + C_IN;
        const float* __restrict__ x2 = x1 + C_IN;
        const float* __restrict__ x3 = x2 + C_IN;
        float h0 = 0.f, h1 = 0.f, h2 = 0.f, h3 = 0.f;
#pragma unroll 4
        for (int c = 0; c < C_IN; ++c) {
            const float w_ = Wl[c * C_OUT + lane];
            h0 = fmaf(x0[c], w_, h0);      // x*[c] are wave-uniform (scalar loads)
            h1 = fmaf(x1[c], w_, h1);
            h2 = fmaf(x2[c], w_, h2);
            h3 = fmaf(x3[c], w_, h3);
        }
        tr[lane][rl + 0] = h0;             // bank = (lane*33+const)%32 -> conflict-free
        tr[lane][rl + 1] = h1;
        tr[lane][rl + 2] = h2;
        tr[lane][rl + 3] = h3;

        float hv[4] = {h0, h1, h2, h3};
#pragma unroll
        for (int k = 0; k < 4; ++k) {
            float p1 = hv[k] * a1l[lane];
            float p2 = hv[k] * a2l[lane];
#pragma unroll
            for (int off = 32; off; off >>= 1) {
                p1 += __shfl_xor(p1, off, 64);
                p2 += __shfl_xor(p2, off, 64);
            }
            if (lane == 0) {
                s1[i0 + rl + k] = p1;
                s2[i0 + rl + k] = p2;
            }
        }
    }
    __syncthreads();

    // write hT[b][f][il + ro], coalesced in ro
#pragma unroll
    for (int it = 0; it < 8; ++it) {
        const int f  = it * 8 + (threadIdx.x >> 5);
        const int ro = threadIdx.x & 31;
        hT[((size_t)b * C_OUT + f) * N_DIM + il + ro] = __float2bfloat16(tr[f][ro]);
    }
}

// ---------------- Kernel B: mask pack + softmax stats ----------------
__global__ __launch_bounds__(256) void gat_stats(
    const float* __restrict__ adj,   // [N,N]
    const float* __restrict__ s1,    // [B*N]
    const float* __restrict__ s2,    // [B*N]
    unsigned long long* __restrict__ mask,  // [N][N/64]
    float* __restrict__ mrow,        // [B*N]
    float* __restrict__ linv)        // [B*N]
{
    const int i    = blockIdx.x;     // 0..N-1
    const int wave = threadIdx.x >> 6;
    const int lane = threadIdx.x & 63;
    const int b0   = wave * 2;       // this wave handles batches b0, b0+1

    const float s1a = s1[(size_t)b0 * N_DIM + i];
    const float s1b = s1[(size_t)(b0 + 1) * N_DIM + i];
    const float* __restrict__ s2a = s2 + (size_t)b0 * N_DIM;
    const float* __restrict__ s2c = s2 + (size_t)(b0 + 1) * N_DIM;
    const float* __restrict__ arow = adj + (size_t)i * N_DIM;

    float m0 = -1e30f, l0 = 0.f, m1 = -1e30f, l1 = 0.f;

    for (int j0 = 0; j0 < N_DIM; j0 += 64) {
        const int j = j0 + lane;
        const bool conn = arow[j] > 0.f;
        if (wave == 0) {
            const unsigned long long bm = __ballot(conn);
            if (lane == 0) mask[(size_t)i * (N_DIM / 64) + (j0 >> 6)] = bm;
        }
        const bool valid = conn || (j == i);
        {
            float e = s1a + s2a[j];
            e = fmaxf(e, 0.01f * e);                  // leaky_relu
            const float ee = valid ? e : -1e30f;
            const float nm = fmaxf(m0, ee);
            const float p  = valid ? __expf(e - nm) : 0.f;
            l0 = l0 * __expf(m0 - nm) + p;
            m0 = nm;
        }
        {
            float e = s1b + s2c[j];
            e = fmaxf(e, 0.01f * e);
            const float ee = valid ? e : -1e30f;
            const float nm = fmaxf(m1, ee);
            const float p  = valid ? __expf(e - nm) : 0.f;
            l1 = l1 * __expf(m1 - nm) + p;
            m1 = nm;
        }
    }
    // cross-lane merge of (m,l)
#pragma unroll
    for (int off = 32; off; off >>= 1) {
        {
            const float om = __shfl_xor(m0, off, 64);
            const float ol = __shfl_xor(l0, off, 64);
            const float nm = fmaxf(m0, om);
            l0 = l0 * __expf(m0 - nm) + ol * __expf(om - nm);
            m0 = nm;
        }
        {
            const float om = __shfl_xor(m1, off, 64);
            const float ol = __shfl_xor(l1, off, 64);
            const float nm = fmaxf(m1, om);
            l1 = l1 * __expf(m1 - nm) + ol * __expf(om - nm);
            m1 = nm;
        }
    }
    if (lane == 0) {
        mrow[(size_t)b0 * N_DIM + i] = m0;
        linv[(size_t)b0 * N_DIM + i] = 1.f / l0;   // diag always valid -> l0 > 0
        mrow[(size_t)(b0 + 1) * N_DIM + i] = m1;
        linv[(size_t)(b0 + 1) * N_DIM + i] = 1.f / l1;
    }
}

// ---------------- Kernel C: MFMA attention ----------------
__global__ __launch_bounds__(256) void gat_attn(
    const __hip_bfloat16* __restrict__ hT,   // [B][C_OUT][N]
    const float* __restrict__ s1,
    const float* __restrict__ s2,
    const unsigned long long* __restrict__ mask,  // [N][N/64]
    const float* __restrict__ mrow,
    const float* __restrict__ linv,
    float* __restrict__ out)                 // [B,N,C_OUT]
{
    __shared__ float accL[4][16][C_OUT];     // 16 KB partial sums

    const int wave = threadIdx.x >> 6;
    const int lane = threadIdx.x & 63;
    const int tb = blockIdx.x;               // 0..1023
    const int b  = tb >> 7;                  // 128 row-tiles per batch
    const int i0 = (tb & 127) * 16;
    const int mloc = lane & 15;
    const int quad = lane >> 4;
    const int i_g  = i0 + mloc;              // this lane's i (local to batch)

    const float s1v = s1[(size_t)b * N_DIM + i_g];
    const float mv  = mrow[(size_t)b * N_DIM + i_g];
    const float lv  = linv[(size_t)b * N_DIM + i_g];
    const float* __restrict__ s2b = s2 + (size_t)b * N_DIM;
    const uint8_t* __restrict__ mB = (const uint8_t*)mask;   // [N][N/8] bytes (LE)
    const __hip_bfloat16* __restrict__ hTb = hT + (size_t)b * C_OUT * N_DIM;

    f32x4 acc0 = {0.f,0.f,0.f,0.f}, acc1 = {0.f,0.f,0.f,0.f};
    f32x4 acc2 = {0.f,0.f,0.f,0.f}, acc3 = {0.f,0.f,0.f,0.f};

    for (int jt = 0; jt < 8; ++jt) {
        const int j0 = wave * 512 + jt * 64;
#pragma unroll
        for (int st = 0; st < 2; ++st) {
            const int bj = j0 + st * 32 + quad * 8;    // this lane's 8 j's (A-frag k)
            const unsigned mbyte = mB[(size_t)i_g * (N_DIM / 8) + (bj >> 3)];
            const f32x4 sA = *(const f32x4*)(s2b + bj);
            const f32x4 sB = *(const f32x4*)(s2b + bj + 4);
            bf16x8 pf;
#pragma unroll
            for (int t = 0; t < 8; ++t) {
                float e = s1v + (t < 4 ? sA[t] : sB[t - 4]);
                e = fmaxf(e, 0.01f * e);               // leaky_relu
                const bool valid = ((mbyte >> t) & 1u) || (bj + t == i_g);
                const float pv = valid ? __expf(e - mv) * lv : 0.f;
                pf[t] = f2bf(pv);
            }
            // B fragments: one b128 load per 16-f block (hT rows are j-contiguous)
            const __hip_bfloat16* hp = hTb + bj;
            const bf16x8 bF0 = *(const bf16x8*)(hp + (size_t)(0 * 16 + mloc) * N_DIM);
            const bf16x8 bF1 = *(const bf16x8*)(hp + (size_t)(1 * 16 + mloc) * N_DIM);
            const bf16x8 bF2 = *(const bf16x8*)(hp + (size_t)(2 * 16 + mloc) * N_DIM);
            const bf16x8 bF3 = *(const bf16x8*)(hp + (size_t)(3 * 16 + mloc) * N_DIM);
            acc0 = __builtin_amdgcn_mfma_f32_16x16x32_bf16(pf, bF0, acc0, 0, 0, 0);
            acc1 = __builtin_amdgcn_mfma_f32_16x16x32_bf16(pf, bF1, acc1, 0, 0, 0);
            acc2 = __builtin_amdgcn_mfma_f32_16x16x32_bf16(pf, bF2, acc2, 0, 0, 0);
            acc3 = __builtin_amdgcn_mfma_f32_16x16x32_bf16(pf, bF3, acc3, 0, 0, 0);
        }
    }

    // C/D layout: row r = quad*4+reg, col f = nb*16+mloc
#pragma unroll
    for (int reg = 0; reg < 4; ++reg) {
        const int r = quad * 4 + reg;
        accL[wave][r][0 * 16 + mloc] = acc0[reg];
        accL[wave][r][1 * 16 + mloc] = acc1[reg];
        accL[wave][r][2 * 16 + mloc] = acc2[reg];
        accL[wave][r][3 * 16 + mloc] = acc3[reg];
    }
    __syncthreads();

    float* __restrict__ ob = out + ((size_t)b * N_DIM + i0) * C_OUT;
    const float* a0 = (const float*)accL[0];
    const float* a1 = (const float*)accL[1];
    const float* a2 = (const float*)accL[2];
    const float* a3 = (const float*)accL[3];
    for (int e = threadIdx.x; e < 16 * C_OUT; e += 256)
        ob[e] = a0[e] + a1[e] + a2[e] + a3[e];
}

extern "C" void kernel_launch(void* const* d_in, const int* in_sizes, int n_in,
                              void* d_out, int out_size, void* d_ws, size_t ws_size,
                              hipStream_t stream) {
    const float* inp = (const float*)d_in[0];   // [8,2048,128]
    const float* adj = (const float*)d_in[1];   // [2048,2048]
    const float* W   = (const float*)d_in[2];   // [128,64]
    const float* a   = (const float*)d_in[3];   // [128]
    float* out = (float*)d_out;                 // [8,2048,64]

    // ws layout (2.75 MB total):
    char* ws = (char*)d_ws;
    __hip_bfloat16* hT = (__hip_bfloat16*)ws;                       // 2 MB
    float* s1 = (float*)(ws + (size_t)2 * 1024 * 1024);             // 64 KB
    float* s2 = s1 + NROWS;                                         // 64 KB
    unsigned long long* mask = (unsigned long long*)(s2 + NROWS);   // 512 KB
    float* mrow = (float*)((char*)mask + (size_t)N_DIM * (N_DIM / 8)); // 64 KB
    float* linv = mrow + NROWS;                                     // 64 KB

    gat_hproj<<<NROWS / 32, 256, 0, stream>>>(inp, W, a, hT, s1, s2);
    gat_stats<<<N_DIM, 256, 0, stream>>>(adj, s1, s2, mask, mrow, linv);
    gat_attn <<<(NROWS / 16), 256, 0, stream>>>(hT, s1, s2, mask, mrow, linv, out);
}

// Round 4
// 151.635 us; speedup vs baseline: 3.4345x; 1.0248x over previous
//
#include <hip/hip_runtime.h>
#include <hip/hip_bf16.h>
#include <cstddef>
#include <cstdint>

// GAT layer: B=8, N=2048, C_IN=128, C_OUT=64, fp32 in/out.
//
// Rank-1 scores: e[b,i,j] = lrelu(s1[b,i] + s2[b,j]); mask = adj>0 | diag.
// lrelu is monotonic => m[b,i] = lrelu(s1[b,i] + max_{valid j} s2[b,j])
// EXACTLY equals the reference row max (fp rounding is monotone). So the
// stats pass needs no exp at all; the softmax denominator l is accumulated
// inside the MFMA kernel (sum of the very p's that feed the MFMA).
//
// A: h = inp@W (W in LDS), hT bf16 [B][C_OUT][N] via LDS transpose, s1, s2.
// B: mask bits (ballot, diag folded in) + per-(b,i) max of s2 -> mrow.
// C: P=exp(e-m) built in MFMA A-frag layout, H as B-frags (b128 from hT),
//    16x16x32 bf16 MFMA; 512-thr blocks, 16 i-rows, 8-way j-split
//    -> 32 waves/CU (round-3 lesson: 29% occupancy made it latency-bound).
//    Epilogue: LDS-reduce 8 partial acc + l, out = acc/l.
//
// ws budget (round-1 lesson: stay well under 4 MB): 2M hT + 128K s1/s2 +
// 512K mask + 64K mrow = 2.71 MB.

#define B_DIM 8
#define N_DIM 2048
#define C_IN  128
#define C_OUT 64
#define NROWS (B_DIM * N_DIM)   // 16384

typedef short bf16x8 __attribute__((ext_vector_type(8)));
typedef short bf16x4 __attribute__((ext_vector_type(4)));
typedef float f32x4  __attribute__((ext_vector_type(4)));

static __device__ __forceinline__ short f2bf(float x) {
    __hip_bfloat16 b = __float2bfloat16(x);
    return *reinterpret_cast<short*>(&b);
}

// ---------------- Kernel A: projection + transpose + s1/s2 ----------------
__global__ __launch_bounds__(256) void gat_hproj(
    const float* __restrict__ inp,   // [B,N,C_IN]
    const float* __restrict__ W,     // [C_IN,C_OUT]
    const float* __restrict__ a,     // [2*C_OUT]
    __hip_bfloat16* __restrict__ hT, // [B][C_OUT][N] bf16
    float* __restrict__ s1,          // [B*N]
    float* __restrict__ s2)          // [B*N]
{
    __shared__ float Wl[C_IN * C_OUT];     // 32 KB
    __shared__ float a1l[C_OUT], a2l[C_OUT];
    __shared__ float tr[C_OUT][17];        // 16-row transpose buffer, padded

    {
        const float4* Wv = (const float4*)W;
        float4* Wd = (float4*)Wl;
        for (int t = threadIdx.x; t < C_IN * C_OUT / 4; t += 256) Wd[t] = Wv[t];
        if (threadIdx.x < C_OUT) {
            a1l[threadIdx.x] = a[threadIdx.x];
            a2l[threadIdx.x] = a[C_OUT + threadIdx.x];
        }
    }
    __syncthreads();

    const int wave = threadIdx.x >> 6;
    const int lane = threadIdx.x & 63;
    const int i0 = blockIdx.x * 16;        // 16 rows per block (never crosses batch)
    const int b  = i0 >> 11;
    const int il = i0 & (N_DIM - 1);
    const int rl = wave * 4;               // this wave's 4 rows

    const float* __restrict__ x0 = inp + (size_t)(i0 + rl) * C_IN;
    const float* __restrict__ x1 = x0 + C_IN;
    const float* __restrict__ x2 = x1 + C_IN;
    const float* __restrict__ x3 = x2 + C_IN;
    float h0 = 0.f, h1 = 0.f, h2 = 0.f, h3 = 0.f;
#pragma unroll 4
    for (int c = 0; c < C_IN; c += 4) {
        const float4 a0 = *(const float4*)(x0 + c);
        const float4 a1 = *(const float4*)(x1 + c);
        const float4 a2 = *(const float4*)(x2 + c);
        const float4 a3 = *(const float4*)(x3 + c);
#pragma unroll
        for (int cc = 0; cc < 4; ++cc) {
            const float w_ = Wl[(c + cc) * C_OUT + lane];
            const float e0 = (cc==0)?a0.x:(cc==1)?a0.y:(cc==2)?a0.z:a0.w;
            const float e1 = (cc==0)?a1.x:(cc==1)?a1.y:(cc==2)?a1.z:a1.w;
            const float e2 = (cc==0)?a2.x:(cc==1)?a2.y:(cc==2)?a2.z:a2.w;
            const float e3 = (cc==0)?a3.x:(cc==1)?a3.y:(cc==2)?a3.z:a3.w;
            h0 = fmaf(e0, w_, h0);
            h1 = fmaf(e1, w_, h1);
            h2 = fmaf(e2, w_, h2);
            h3 = fmaf(e3, w_, h3);
        }
    }
    tr[lane][rl + 0] = h0;                 // stride 17: conflict-free
    tr[lane][rl + 1] = h1;
    tr[lane][rl + 2] = h2;
    tr[lane][rl + 3] = h3;

    float hv[4] = {h0, h1, h2, h3};
#pragma unroll
    for (int k = 0; k < 4; ++k) {
        float p1 = hv[k] * a1l[lane];
        float p2 = hv[k] * a2l[lane];
#pragma unroll
        for (int off = 32; off; off >>= 1) {
            p1 += __shfl_xor(p1, off, 64);
            p2 += __shfl_xor(p2, off, 64);
        }
        if (lane == 0) {
            s1[i0 + rl + k] = p1;
            s2[i0 + rl + k] = p2;
        }
    }
    __syncthreads();

    // hT[b][f][il+ro4..+4): thread t -> f = t>>2, ro4 = (t&3)*4
    const int f   = threadIdx.x >> 2;
    const int ro4 = (threadIdx.x & 3) * 4;
    bf16x4 v;
    v[0] = f2bf(tr[f][ro4 + 0]);
    v[1] = f2bf(tr[f][ro4 + 1]);
    v[2] = f2bf(tr[f][ro4 + 2]);
    v[3] = f2bf(tr[f][ro4 + 3]);
    *(bf16x4*)(hT + ((size_t)b * C_OUT + f) * N_DIM + il + ro4) = v;
}

// ---------------- Kernel B: mask pack (with diag) + max-s2 stats ----------------
__global__ __launch_bounds__(256) void gat_stats(
    const float* __restrict__ adj,   // [N,N]
    const float* __restrict__ s1,    // [B*N]
    const float* __restrict__ s2,    // [B*N]
    unsigned long long* __restrict__ mask,  // [N][N/64], diag bit included
    float* __restrict__ mrow)        // [B*N]: lrelu(s1 + max valid s2)
{
    __shared__ float red[4][B_DIM];
    const int i    = blockIdx.x;     // 0..N-1
    const int wave = threadIdx.x >> 6;
    const int lane = threadIdx.x & 63;
    const float* __restrict__ arow = adj + (size_t)i * N_DIM;

    float mx[B_DIM];
#pragma unroll
    for (int b = 0; b < B_DIM; ++b) mx[b] = -1e30f;

#pragma unroll 2
    for (int it = 0; it < 8; ++it) {
        const int j = wave * 512 + it * 64 + lane;
        const bool conn = (arow[j] > 0.f) || (j == i);   // diag folded in
        const unsigned long long bm = __ballot(conn);
        if (lane == 0) mask[(size_t)i * (N_DIM / 64) + (j >> 6)] = bm;
#pragma unroll
        for (int b = 0; b < B_DIM; ++b) {
            const float v = s2[(size_t)b * N_DIM + j];
            mx[b] = conn ? fmaxf(mx[b], v) : mx[b];
        }
    }
#pragma unroll
    for (int off = 32; off; off >>= 1)
#pragma unroll
        for (int b = 0; b < B_DIM; ++b)
            mx[b] = fmaxf(mx[b], __shfl_xor(mx[b], off, 64));
    if (lane == 0)
#pragma unroll
        for (int b = 0; b < B_DIM; ++b) red[wave][b] = mx[b];
    __syncthreads();

    if (threadIdx.x < B_DIM) {
        const int b = threadIdx.x;
        const float mxf = fmaxf(fmaxf(red[0][b], red[1][b]),
                                fmaxf(red[2][b], red[3][b]));
        const float z = s1[(size_t)b * N_DIM + i] + mxf;
        mrow[(size_t)b * N_DIM + i] = fmaxf(z, 0.01f * z);   // lrelu, monotone => exact ref max
    }
}

// ---------------- Kernel C: MFMA attention, l fused ----------------
__global__ __launch_bounds__(512, 8) void gat_attn(
    const __hip_bfloat16* __restrict__ hT,        // [B][C_OUT][N]
    const float* __restrict__ s1,
    const float* __restrict__ s2,
    const unsigned long long* __restrict__ mask,  // [N][N/64]
    const float* __restrict__ mrow,
    float* __restrict__ out)                      // [B,N,C_OUT]
{
    __shared__ float accL[8][16][C_OUT];   // 32 KB partial sums
    __shared__ float lred[8][16];

    const int wave = threadIdx.x >> 6;     // 0..7 (8-way j-split)
    const int lane = threadIdx.x & 63;
    const int tb = blockIdx.x;             // 0..1023
    const int b  = tb >> 7;                // 128 row-tiles per batch
    const int i0 = (tb & 127) * 16;
    const int mloc = lane & 15;
    const int quad = lane >> 4;
    const int i_g  = i0 + mloc;

    const float s1v = s1[(size_t)b * N_DIM + i_g];
    const float mv  = mrow[(size_t)b * N_DIM + i_g];
    const float* __restrict__ s2b = s2 + (size_t)b * N_DIM;
    const unsigned long long* __restrict__ mrowp = mask + (size_t)i_g * (N_DIM / 64);
    const __hip_bfloat16* __restrict__ hTb = hT + (size_t)b * C_OUT * N_DIM;

    f32x4 acc0 = {0.f,0.f,0.f,0.f}, acc1 = {0.f,0.f,0.f,0.f};
    f32x4 acc2 = {0.f,0.f,0.f,0.f}, acc3 = {0.f,0.f,0.f,0.f};
    float lacc = 0.f;

#pragma unroll
    for (int jt = 0; jt < 4; ++jt) {
        const int j0 = wave * 256 + jt * 64;
        const unsigned long long mword = mrowp[j0 >> 6];
#pragma unroll
        for (int st = 0; st < 2; ++st) {
            const int bj = j0 + st * 32 + quad * 8;  // this lane's 8 j's (A-frag k)
            const unsigned mb = (unsigned)(mword >> (st * 32 + quad * 8)) & 0xffu;
            const f32x4 sA = *(const f32x4*)(s2b + bj);
            const f32x4 sB = *(const f32x4*)(s2b + bj + 4);
            bf16x8 pf;
#pragma unroll
            for (int t = 0; t < 8; ++t) {
                const float zz = s1v + (t < 4 ? sA[t] : sB[t - 4]);
                const float e = fmaxf(zz, 0.01f * zz);          // leaky_relu
                const float p = ((mb >> t) & 1u) ? __expf(e - mv) : 0.f;
                lacc += p;
                pf[t] = f2bf(p);
            }
            const __hip_bfloat16* hp = hTb + bj;
            const bf16x8 bF0 = *(const bf16x8*)(hp + (size_t)(0 * 16 + mloc) * N_DIM);
            const bf16x8 bF1 = *(const bf16x8*)(hp + (size_t)(1 * 16 + mloc) * N_DIM);
            const bf16x8 bF2 = *(const bf16x8*)(hp + (size_t)(2 * 16 + mloc) * N_DIM);
            const bf16x8 bF3 = *(const bf16x8*)(hp + (size_t)(3 * 16 + mloc) * N_DIM);
            acc0 = __builtin_amdgcn_mfma_f32_16x16x32_bf16(pf, bF0, acc0, 0, 0, 0);
            acc1 = __builtin_amdgcn_mfma_f32_16x16x32_bf16(pf, bF1, acc1, 0, 0, 0);
            acc2 = __builtin_amdgcn_mfma_f32_16x16x32_bf16(pf, bF2, acc2, 0, 0, 0);
            acc3 = __builtin_amdgcn_mfma_f32_16x16x32_bf16(pf, bF3, acc3, 0, 0, 0);
        }
    }

    // l: lane holds row i = mloc; sum over quads, then over waves via LDS
    lacc += __shfl_xor(lacc, 16, 64);
    lacc += __shfl_xor(lacc, 32, 64);
    if (quad == 0) lred[wave][mloc] = lacc;

    // C/D layout: row r = quad*4+reg, col f = nb*16+mloc
#pragma unroll
    for (int reg = 0; reg < 4; ++reg) {
        const int r = quad * 4 + reg;
        accL[wave][r][0 * 16 + mloc] = acc0[reg];
        accL[wave][r][1 * 16 + mloc] = acc1[reg];
        accL[wave][r][2 * 16 + mloc] = acc2[reg];
        accL[wave][r][3 * 16 + mloc] = acc3[reg];
    }
    __syncthreads();

    const float* aflat = (const float*)accL;
    float* __restrict__ ob = out + ((size_t)b * N_DIM + i0) * C_OUT;
#pragma unroll
    for (int e = threadIdx.x; e < 16 * C_OUT; e += 512) {
        const int r = e >> 6;
        float s = 0.f, ls = 0.f;
#pragma unroll
        for (int w = 0; w < 8; ++w) {
            s  += aflat[w * 16 * C_OUT + e];
            ls += lred[w][r];
        }
        ob[e] = s / ls;
    }
}

extern "C" void kernel_launch(void* const* d_in, const int* in_sizes, int n_in,
                              void* d_out, int out_size, void* d_ws, size_t ws_size,
                              hipStream_t stream) {
    const float* inp = (const float*)d_in[0];   // [8,2048,128]
    const float* adj = (const float*)d_in[1];   // [2048,2048]
    const float* W   = (const float*)d_in[2];   // [128,64]
    const float* a   = (const float*)d_in[3];   // [128]
    float* out = (float*)d_out;                 // [8,2048,64]

    // ws layout (2.71 MB total):
    char* ws = (char*)d_ws;
    __hip_bfloat16* hT = (__hip_bfloat16*)ws;                       // 2 MB
    float* s1 = (float*)(ws + (size_t)2 * 1024 * 1024);             // 64 KB
    float* s2 = s1 + NROWS;                                         // 64 KB
    unsigned long long* mask = (unsigned long long*)(s2 + NROWS);   // 512 KB
    float* mrow = (float*)((char*)mask + (size_t)N_DIM * (N_DIM / 8)); // 64 KB

    gat_hproj<<<NROWS / 16, 256, 0, stream>>>(inp, W, a, hT, s1, s2);
    gat_stats<<<N_DIM, 256, 0, stream>>>(adj, s1, s2, mask, mrow);
    gat_attn <<<NROWS / 16, 512, 0, stream>>>(hT, s1, s2, mask, mrow, out);
}

// Round 5
// 137.288 us; speedup vs baseline: 3.7934x; 1.1045x over previous
//
#include <hip/hip_runtime.h>
#include <hip/hip_bf16.h>
#include <cstddef>
#include <cstdint>

// GAT layer: B=8, N=2048, C_IN=128, C_OUT=64, fp32 in/out.
//
// Rank-1 scores: e[b,i,j] = lrelu(s1[b,i] + s2[b,j]); mask = adj>0 | diag.
// lrelu monotone => row max m = lrelu(s1_i + max_valid s2_j) exactly; exp-free
// stats pass; softmax denominator l accumulated inside the MFMA kernel.
//
// A: h = inp@W (W in LDS), hT bf16 [B][C_OUT][N] via LDS transpose, s1, s2.
// B: mask bits (ballot, diag folded) + per-(b,i) max of valid s2 -> mrow.
// C: 32 i-rows/block, 512 thr; j swept in 256-wide chunks; hT chunk (32 KB)
//    DMA'd to LDS via global_load_lds (XOR-swizzled for conflict-free
//    ds_read_b128 B-frags), shared by all 8 waves (2 i-halves x 4 j-quarters).
//    P=exp(e-m) built in MFMA A-frag layout; 16x16x32 bf16 MFMA; epilogue
//    reduces 4 j-quarter partials + l in LDS (reusing the staging buffer).
//    Round-3/4 lesson: raw per-wave hT loads (16 lines, 4KB apart) were
//    latency-exposed at low occupancy; LDS staging + (512,4) fixes both.
//
// ws budget (round-1 lesson: stay well under 4 MB): 2M hT + 128K s1/s2 +
// 512K mask + 64K mrow = 2.71 MB.

#define B_DIM 8
#define N_DIM 2048
#define C_IN  128
#define C_OUT 64
#define NROWS (B_DIM * N_DIM)   // 16384

typedef short bf16x8 __attribute__((ext_vector_type(8)));
typedef short bf16x4 __attribute__((ext_vector_type(4)));
typedef float f32x4  __attribute__((ext_vector_type(4)));

static __device__ __forceinline__ short f2bf(float x) {
    __hip_bfloat16 b = __float2bfloat16(x);
    return *reinterpret_cast<short*>(&b);
}

// ---------------- Kernel A: projection + transpose + s1/s2 ----------------
__global__ __launch_bounds__(256) void gat_hproj(
    const float* __restrict__ inp,   // [B,N,C_IN]
    const float* __restrict__ W,     // [C_IN,C_OUT]
    const float* __restrict__ a,     // [2*C_OUT]
    __hip_bfloat16* __restrict__ hT, // [B][C_OUT][N] bf16
    float* __restrict__ s1,          // [B*N]
    float* __restrict__ s2)          // [B*N]
{
    __shared__ float Wl[C_IN * C_OUT];     // 32 KB
    __shared__ float a1l[C_OUT], a2l[C_OUT];
    __shared__ float tr[C_OUT][17];        // 16-row transpose buffer, padded

    {
        const float4* Wv = (const float4*)W;
        float4* Wd = (float4*)Wl;
        for (int t = threadIdx.x; t < C_IN * C_OUT / 4; t += 256) Wd[t] = Wv[t];
        if (threadIdx.x < C_OUT) {
            a1l[threadIdx.x] = a[threadIdx.x];
            a2l[threadIdx.x] = a[C_OUT + threadIdx.x];
        }
    }
    __syncthreads();

    const int wave = threadIdx.x >> 6;
    const int lane = threadIdx.x & 63;
    const int i0 = blockIdx.x * 16;        // 16 rows per block (never crosses batch)
    const int b  = i0 >> 11;
    const int il = i0 & (N_DIM - 1);
    const int rl = wave * 4;               // this wave's 4 rows

    const float* __restrict__ x0 = inp + (size_t)(i0 + rl) * C_IN;
    const float* __restrict__ x1 = x0 + C_IN;
    const float* __restrict__ x2 = x1 + C_IN;
    const float* __restrict__ x3 = x2 + C_IN;
    float h0 = 0.f, h1 = 0.f, h2 = 0.f, h3 = 0.f;
#pragma unroll 4
    for (int c = 0; c < C_IN; c += 4) {
        const float4 a0 = *(const float4*)(x0 + c);
        const float4 a1 = *(const float4*)(x1 + c);
        const float4 a2 = *(const float4*)(x2 + c);
        const float4 a3 = *(const float4*)(x3 + c);
#pragma unroll
        for (int cc = 0; cc < 4; ++cc) {
            const float w_ = Wl[(c + cc) * C_OUT + lane];
            const float e0 = (cc==0)?a0.x:(cc==1)?a0.y:(cc==2)?a0.z:a0.w;
            const float e1 = (cc==0)?a1.x:(cc==1)?a1.y:(cc==2)?a1.z:a1.w;
            const float e2 = (cc==0)?a2.x:(cc==1)?a2.y:(cc==2)?a2.z:a2.w;
            const float e3 = (cc==0)?a3.x:(cc==1)?a3.y:(cc==2)?a3.z:a3.w;
            h0 = fmaf(e0, w_, h0);
            h1 = fmaf(e1, w_, h1);
            h2 = fmaf(e2, w_, h2);
            h3 = fmaf(e3, w_, h3);
        }
    }
    tr[lane][rl + 0] = h0;                 // stride 17: conflict-free
    tr[lane][rl + 1] = h1;
    tr[lane][rl + 2] = h2;
    tr[lane][rl + 3] = h3;

    float hv[4] = {h0, h1, h2, h3};
#pragma unroll
    for (int k = 0; k < 4; ++k) {
        float p1 = hv[k] * a1l[lane];
        float p2 = hv[k] * a2l[lane];
#pragma unroll
        for (int off = 32; off; off >>= 1) {
            p1 += __shfl_xor(p1, off, 64);
            p2 += __shfl_xor(p2, off, 64);
        }
        if (lane == 0) {
            s1[i0 + rl + k] = p1;
            s2[i0 + rl + k] = p2;
        }
    }
    __syncthreads();

    // hT[b][f][il+ro4..+4): thread t -> f = t>>2, ro4 = (t&3)*4
    const int f   = threadIdx.x >> 2;
    const int ro4 = (threadIdx.x & 3) * 4;
    bf16x4 v;
    v[0] = f2bf(tr[f][ro4 + 0]);
    v[1] = f2bf(tr[f][ro4 + 1]);
    v[2] = f2bf(tr[f][ro4 + 2]);
    v[3] = f2bf(tr[f][ro4 + 3]);
    *(bf16x4*)(hT + ((size_t)b * C_OUT + f) * N_DIM + il + ro4) = v;
}

// ---------------- Kernel B: mask pack (with diag) + max-s2 stats ----------------
__global__ __launch_bounds__(256) void gat_stats(
    const float* __restrict__ adj,   // [N,N]
    const float* __restrict__ s1,    // [B*N]
    const float* __restrict__ s2,    // [B*N]
    unsigned long long* __restrict__ mask,  // [N][N/64], diag bit included
    float* __restrict__ mrow)        // [B*N]: lrelu(s1 + max valid s2)
{
    __shared__ float red[4][B_DIM];
    const int i    = blockIdx.x;     // 0..N-1
    const int wave = threadIdx.x >> 6;
    const int lane = threadIdx.x & 63;
    const float* __restrict__ arow = adj + (size_t)i * N_DIM;

    float mx[B_DIM];
#pragma unroll
    for (int b = 0; b < B_DIM; ++b) mx[b] = -1e30f;

#pragma unroll 2
    for (int it = 0; it < 8; ++it) {
        const int j = wave * 512 + it * 64 + lane;
        const bool conn = (arow[j] > 0.f) || (j == i);   // diag folded in
        const unsigned long long bm = __ballot(conn);
        if (lane == 0) mask[(size_t)i * (N_DIM / 64) + (j >> 6)] = bm;
#pragma unroll
        for (int b = 0; b < B_DIM; ++b) {
            const float v = s2[(size_t)b * N_DIM + j];
            mx[b] = conn ? fmaxf(mx[b], v) : mx[b];
        }
    }
#pragma unroll
    for (int off = 32; off; off >>= 1)
#pragma unroll
        for (int b = 0; b < B_DIM; ++b)
            mx[b] = fmaxf(mx[b], __shfl_xor(mx[b], off, 64));
    if (lane == 0)
#pragma unroll
        for (int b = 0; b < B_DIM; ++b) red[wave][b] = mx[b];
    __syncthreads();

    if (threadIdx.x < B_DIM) {
        const int b = threadIdx.x;
        const float mxf = fmaxf(fmaxf(red[0][b], red[1][b]),
                                fmaxf(red[2][b], red[3][b]));
        const float z = s1[(size_t)b * N_DIM + i] + mxf;
        mrow[(size_t)b * N_DIM + i] = fmaxf(z, 0.01f * z);   // lrelu, monotone => exact ref max
    }
}

// ---------------- Kernel C: MFMA attention, LDS-staged hT, l fused ----------------
// Block: 32 i-rows, 512 thr (8 waves = 2 i-halves x 4 j-quarters).
// j swept in 8 chunks of 256; per chunk: 32 KB hT slice DMA'd to LDS
// (swizzled: chunk c of row f stored at cS = (c&16) | ((c^(f&15))&15)).
__global__ __launch_bounds__(512, 4) void gat_attn(
    const __hip_bfloat16* __restrict__ hT,        // [B][C_OUT][N]
    const float* __restrict__ s1,
    const float* __restrict__ s2,
    const unsigned long long* __restrict__ mask,  // [N][N/64]
    const float* __restrict__ mrow,
    float* __restrict__ out)                      // [B,N,C_OUT]
{
    __shared__ __align__(16) char smem[32768];    // staging buffer / epilogue accL
    __shared__ float lred[8][16];

    const int wave = threadIdx.x >> 6;     // 0..7
    const int lane = threadIdx.x & 63;
    const int half = wave >> 2;            // i-half (0/1)
    const int jq   = wave & 3;             // j-quarter within chunk
    const int tb = blockIdx.x;             // 0..511
    const int b  = tb >> 6;                // 64 row-tiles of 32 per batch
    const int i0 = (tb & 63) * 32;
    const int mloc = lane & 15;
    const int quad = lane >> 4;
    const int i_g  = i0 + half * 16 + mloc;

    const float s1v = s1[(size_t)b * N_DIM + i_g];
    const float mv  = mrow[(size_t)b * N_DIM + i_g];
    const float* __restrict__ s2b = s2 + (size_t)b * N_DIM;
    const uint8_t* __restrict__ mB = (const uint8_t*)mask;   // [N][N/8] bytes (LE)
    const char* __restrict__ hTb = (const char*)(hT + (size_t)b * C_OUT * N_DIM);

    f32x4 acc0 = {0.f,0.f,0.f,0.f}, acc1 = {0.f,0.f,0.f,0.f};
    f32x4 acc2 = {0.f,0.f,0.f,0.f}, acc3 = {0.f,0.f,0.f,0.f};
    float lacc = 0.f;

    for (int jc = 0; jc < 8; ++jc) {
        const int jbase = jc * 256;
        __syncthreads();                   // LDS free for overwrite
        // stage hT[b][0:64][jbase:+256) -> LDS, swizzled; 4 DMA instr/wave
#pragma unroll
        for (int q = 0; q < 4; ++q) {
            const int p = (wave * 4 + q) * 64 + lane;       // 0..2047
            const int f  = p >> 5;
            const int cs = p & 31;
            const int c  = (cs & 16) | ((cs ^ (f & 15)) & 15);
            const char* gp = hTb + ((size_t)f * N_DIM + jbase) * 2 + c * 16;
            char* lp = smem + (wave * 4 + q) * 1024;        // + lane*16 implicit
            __builtin_amdgcn_global_load_lds(
                (const __attribute__((address_space(1))) void*)gp,
                (__attribute__((address_space(3))) void*)lp, 16, 0, 0);
        }
        __syncthreads();                   // vmcnt(0) drained by barrier

#pragma unroll
        for (int st = 0; st < 2; ++st) {
            const int bjl = jq * 64 + st * 32 + quad * 8;   // within-chunk j
            const int jg  = jbase + bjl;
            const int cA  = bjl >> 3;                        // chunk idx 0..31
            const unsigned mb = mB[(size_t)i_g * (N_DIM / 8) + (jg >> 3)];
            const f32x4 sA = *(const f32x4*)(s2b + jg);
            const f32x4 sB = *(const f32x4*)(s2b + jg + 4);
            bf16x8 pf;
#pragma unroll
            for (int t = 0; t < 8; ++t) {
                const float zz = s1v + (t < 4 ? sA[t] : sB[t - 4]);
                const float e = fmaxf(zz, 0.01f * zz);       // leaky_relu
                const float p = ((mb >> t) & 1u) ? __expf(e - mv) : 0.f;
                lacc += p;
                pf[t] = f2bf(p);
            }
#pragma unroll
            for (int nb = 0; nb < 4; ++nb) {
                const int f  = nb * 16 + mloc;
                const int cS = (cA & 16) | ((cA ^ (f & 15)) & 15);
                const bf16x8 bF = *(const bf16x8*)(smem + (f * 32 + cS) * 16);
                if (nb == 0) acc0 = __builtin_amdgcn_mfma_f32_16x16x32_bf16(pf, bF, acc0, 0, 0, 0);
                if (nb == 1) acc1 = __builtin_amdgcn_mfma_f32_16x16x32_bf16(pf, bF, acc1, 0, 0, 0);
                if (nb == 2) acc2 = __builtin_amdgcn_mfma_f32_16x16x32_bf16(pf, bF, acc2, 0, 0, 0);
                if (nb == 3) acc3 = __builtin_amdgcn_mfma_f32_16x16x32_bf16(pf, bF, acc3, 0, 0, 0);
            }
        }
    }
    __syncthreads();                       // staging done; reuse smem as accL

    // l: sum over quads -> per-row; waves cover disjoint j -> sum in epilogue
    lacc += __shfl_xor(lacc, 16, 64);
    lacc += __shfl_xor(lacc, 32, 64);
    if (quad == 0) lred[wave][mloc] = lacc;

    // C/D layout: row r = quad*4+reg, col f = nb*16+mloc
    float* accL = (float*)smem;            // [8][16][64]
#pragma unroll
    for (int reg = 0; reg < 4; ++reg) {
        const int r = quad * 4 + reg;
        accL[(wave * 16 + r) * 64 + 0 * 16 + mloc] = acc0[reg];
        accL[(wave * 16 + r) * 64 + 1 * 16 + mloc] = acc1[reg];
        accL[(wave * 16 + r) * 64 + 2 * 16 + mloc] = acc2[reg];
        accL[(wave * 16 + r) * 64 + 3 * 16 + mloc] = acc3[reg];
    }
    __syncthreads();

    float* __restrict__ ob = out + ((size_t)b * N_DIM + i0) * C_OUT;
#pragma unroll
    for (int e = threadIdx.x; e < 32 * C_OUT; e += 512) {
        const int R = e >> 6;              // output row 0..31
        const int hf = R >> 4;             // which i-half
        const int r  = R & 15;
        float s = 0.f, ls = 0.f;
#pragma unroll
        for (int q = 0; q < 4; ++q) {
            const int w = hf * 4 + q;
            s  += accL[(w * 16 + r) * 64 + (e & 63)];
            ls += lred[w][r];
        }
        ob[e] = s / ls;
    }
}

extern "C" void kernel_launch(void* const* d_in, const int* in_sizes, int n_in,
                              void* d_out, int out_size, void* d_ws, size_t ws_size,
                              hipStream_t stream) {
    const float* inp = (const float*)d_in[0];   // [8,2048,128]
    const float* adj = (const float*)d_in[1];   // [2048,2048]
    const float* W   = (const float*)d_in[2];   // [128,64]
    const float* a   = (const float*)d_in[3];   // [128]
    float* out = (float*)d_out;                 // [8,2048,64]

    // ws layout (2.71 MB total):
    char* ws = (char*)d_ws;
    __hip_bfloat16* hT = (__hip_bfloat16*)ws;                       // 2 MB
    float* s1 = (float*)(ws + (size_t)2 * 1024 * 1024);             // 64 KB
    float* s2 = s1 + NROWS;                                         // 64 KB
    unsigned long long* mask = (unsigned long long*)(s2 + NROWS);   // 512 KB
    float* mrow = (float*)((char*)mask + (size_t)N_DIM * (N_DIM / 8)); // 64 KB

    gat_hproj<<<NROWS / 16, 256, 0, stream>>>(inp, W, a, hT, s1, s2);
    gat_stats<<<N_DIM, 256, 0, stream>>>(adj, s1, s2, mask, mrow);
    gat_attn <<<NROWS / 32, 512, 0, stream>>>(hT, s1, s2, mask, mrow, out);
}

// Round 6
// 119.062 us; speedup vs baseline: 4.3741x; 1.1531x over previous
//
#include <hip/hip_runtime.h>
#include <hip/hip_bf16.h>
#include <cstddef>
#include <cstdint>

// GAT layer: B=8, N=2048, C_IN=128, C_OUT=64, fp32 in/out.
//
// Rank-1 scores: e[b,i,j] = lrelu(s1[b,i] + s2[b,j]); mask = adj>0 | diag.
// UNNORMALIZED softmax (round-6): e is bounded (|e| <= ~30 => exp fits fp32/bf16
// easily), and softmax is shift-invariant, so we skip the row-max entirely:
// p = exp(e), out = (sum p_j h_j) / (sum p_j). This kills the whole stats
// max-scan AND decouples mask-packing from the projection -> one fused kernel.
// exp via native exp2: s1,s2 are pre-scaled by log2(e) (lrelu commutes with
// positive scaling, exactly).
//
// K1 (gat_prep, 3072 blocks): blocks [0,1024) = projection (h=inp@W, W in LDS,
//     hT bf16 [B][C_OUT][N] via LDS transpose, s1,s2 scaled); blocks
//     [1024,3072) = adj -> bitmask (ballot, diag folded in).
// K2 (gat_attn): 32 i-rows/block, 512 thr (2 i-halves x 4 j-quarters); j in
//     256-chunks; hT chunk DMA'd to LDS via global_load_lds, DOUBLE-BUFFERED
//     (issue chunk c while computing c-1; vmcnt drains at the barrier, hidden
//     under a full compute phase). XOR-swizzled for conflict-free ds_read_b128.
//     P=exp2(e') built in MFMA A-frag layout; 16x16x32 bf16 MFMA; l fused.
//
// ws budget (round-1 lesson: stay well under 4 MB): 2M hT + 128K s1/s2 +
// 512K mask = 2.65 MB.

#define B_DIM 8
#define N_DIM 2048
#define C_IN  128
#define C_OUT 64
#define NROWS (B_DIM * N_DIM)   // 16384
#define LOG2E 1.4426950408889634f

typedef short bf16x8 __attribute__((ext_vector_type(8)));
typedef short bf16x4 __attribute__((ext_vector_type(4)));
typedef float f32x4  __attribute__((ext_vector_type(4)));

static __device__ __forceinline__ short f2bf(float x) {
    __hip_bfloat16 b = __float2bfloat16(x);
    return *reinterpret_cast<short*>(&b);
}

// ---------------- Kernel 1: fused projection + mask-pack ----------------
__global__ __launch_bounds__(256) void gat_prep(
    const float* __restrict__ inp,   // [B,N,C_IN]
    const float* __restrict__ W,     // [C_IN,C_OUT]
    const float* __restrict__ a,     // [2*C_OUT]
    const float* __restrict__ adj,   // [N,N]
    __hip_bfloat16* __restrict__ hT, // [B][C_OUT][N] bf16
    float* __restrict__ s1,          // [B*N], pre-scaled by log2(e)
    float* __restrict__ s2,          // [B*N], pre-scaled by log2(e)
    unsigned long long* __restrict__ mask)  // [N][N/64], diag folded in
{
    __shared__ float Wl[C_IN * C_OUT];     // 32 KB
    __shared__ float a1l[C_OUT], a2l[C_OUT];
    __shared__ float tr[C_OUT][17];        // 16-row transpose buffer, padded

    if (blockIdx.x >= 1024) {
        // ---- mask-pack block: one adj row ----
        const int i    = blockIdx.x - 1024;
        const int wave = threadIdx.x >> 6;
        const int lane = threadIdx.x & 63;
        const float* __restrict__ arow = adj + (size_t)i * N_DIM;
#pragma unroll
        for (int it = 0; it < 8; ++it) {
            const int j = wave * 512 + it * 64 + lane;
            const bool conn = (arow[j] > 0.f) || (j == i);   // diag folded in
            const unsigned long long bm = __ballot(conn);
            if (lane == 0) mask[(size_t)i * (N_DIM / 64) + (j >> 6)] = bm;
        }
        return;
    }

    // ---- projection block: 16 rows ----
    {
        const float4* Wv = (const float4*)W;
        float4* Wd = (float4*)Wl;
        for (int t = threadIdx.x; t < C_IN * C_OUT / 4; t += 256) Wd[t] = Wv[t];
        if (threadIdx.x < C_OUT) {
            a1l[threadIdx.x] = a[threadIdx.x];
            a2l[threadIdx.x] = a[C_OUT + threadIdx.x];
        }
    }
    __syncthreads();

    const int wave = threadIdx.x >> 6;
    const int lane = threadIdx.x & 63;
    const int i0 = blockIdx.x * 16;        // 16 rows per block (never crosses batch)
    const int b  = i0 >> 11;
    const int il = i0 & (N_DIM - 1);
    const int rl = wave * 4;               // this wave's 4 rows

    const float* __restrict__ x0 = inp + (size_t)(i0 + rl) * C_IN;
    const float* __restrict__ x1 = x0 + C_IN;
    const float* __restrict__ x2 = x1 + C_IN;
    const float* __restrict__ x3 = x2 + C_IN;
    float h0 = 0.f, h1 = 0.f, h2 = 0.f, h3 = 0.f;
#pragma unroll 4
    for (int c = 0; c < C_IN; c += 4) {
        const float4 a0 = *(const float4*)(x0 + c);
        const float4 a1 = *(const float4*)(x1 + c);
        const float4 a2 = *(const float4*)(x2 + c);
        const float4 a3 = *(const float4*)(x3 + c);
#pragma unroll
        for (int cc = 0; cc < 4; ++cc) {
            const float w_ = Wl[(c + cc) * C_OUT + lane];
            const float e0 = (cc==0)?a0.x:(cc==1)?a0.y:(cc==2)?a0.z:a0.w;
            const float e1 = (cc==0)?a1.x:(cc==1)?a1.y:(cc==2)?a1.z:a1.w;
            const float e2 = (cc==0)?a2.x:(cc==1)?a2.y:(cc==2)?a2.z:a2.w;
            const float e3 = (cc==0)?a3.x:(cc==1)?a3.y:(cc==2)?a3.z:a3.w;
            h0 = fmaf(e0, w_, h0);
            h1 = fmaf(e1, w_, h1);
            h2 = fmaf(e2, w_, h2);
            h3 = fmaf(e3, w_, h3);
        }
    }
    tr[lane][rl + 0] = h0;                 // stride 17: conflict-free
    tr[lane][rl + 1] = h1;
    tr[lane][rl + 2] = h2;
    tr[lane][rl + 3] = h3;

    float hv[4] = {h0, h1, h2, h3};
#pragma unroll
    for (int k = 0; k < 4; ++k) {
        float p1 = hv[k] * a1l[lane];
        float p2 = hv[k] * a2l[lane];
#pragma unroll
        for (int off = 32; off; off >>= 1) {
            p1 += __shfl_xor(p1, off, 64);
            p2 += __shfl_xor(p2, off, 64);
        }
        if (lane == 0) {
            s1[i0 + rl + k] = p1 * LOG2E;  // pre-scale: exp(x)=exp2(x*log2e)
            s2[i0 + rl + k] = p2 * LOG2E;
        }
    }
    __syncthreads();

    // hT[b][f][il+ro4..+4): thread t -> f = t>>2, ro4 = (t&3)*4
    const int f   = threadIdx.x >> 2;
    const int ro4 = (threadIdx.x & 3) * 4;
    bf16x4 v;
    v[0] = f2bf(tr[f][ro4 + 0]);
    v[1] = f2bf(tr[f][ro4 + 1]);
    v[2] = f2bf(tr[f][ro4 + 2]);
    v[3] = f2bf(tr[f][ro4 + 3]);
    *(bf16x4*)(hT + ((size_t)b * C_OUT + f) * N_DIM + il + ro4) = v;
}

// ---------------- Kernel 2: MFMA attention, double-buffered LDS ----------------
__global__ __launch_bounds__(512, 4) void gat_attn(
    const __hip_bfloat16* __restrict__ hT,        // [B][C_OUT][N]
    const float* __restrict__ s1,
    const float* __restrict__ s2,
    const unsigned long long* __restrict__ mask,  // [N][N/64]
    float* __restrict__ out)                      // [B,N,C_OUT]
{
    __shared__ __align__(16) char smem[2][32768]; // double buffer / epilogue accL
    __shared__ float lred[8][16];

    const int wave = threadIdx.x >> 6;     // 0..7
    const int lane = threadIdx.x & 63;
    const int half = wave >> 2;            // i-half (0/1)
    const int jq   = wave & 3;             // j-quarter within chunk
    const int tb = blockIdx.x;             // 0..511
    const int b  = tb >> 6;                // 64 row-tiles of 32 per batch
    const int i0 = (tb & 63) * 32;
    const int mloc = lane & 15;
    const int quad = lane >> 4;
    const int i_g  = i0 + half * 16 + mloc;

    const float s1v = s1[(size_t)b * N_DIM + i_g];
    const float* __restrict__ s2b = s2 + (size_t)b * N_DIM;
    const uint8_t* __restrict__ mB = (const uint8_t*)mask;   // [N][N/8] bytes (LE)
    const char* __restrict__ hTb = (const char*)(hT + (size_t)b * C_OUT * N_DIM);

    f32x4 acc0 = {0.f,0.f,0.f,0.f}, acc1 = {0.f,0.f,0.f,0.f};
    f32x4 acc2 = {0.f,0.f,0.f,0.f}, acc3 = {0.f,0.f,0.f,0.f};
    float lacc = 0.f;

    // compute one 256-j chunk from LDS buffer `buf`
    auto compute_chunk = [&](int jc, const char* buf) {
#pragma unroll
        for (int st = 0; st < 2; ++st) {
            const int bjl = jq * 64 + st * 32 + quad * 8;   // within-chunk j
            const int jg  = jc * 256 + bjl;
            const int cA  = bjl >> 3;                       // chunk idx 0..31
            const unsigned mb = mB[(size_t)i_g * (N_DIM / 8) + (jg >> 3)];
            const f32x4 sA = *(const f32x4*)(s2b + jg);
            const f32x4 sB = *(const f32x4*)(s2b + jg + 4);
            bf16x8 pf;
#pragma unroll
            for (int t = 0; t < 8; ++t) {
                const float zz = s1v + (t < 4 ? sA[t] : sB[t - 4]);
                const float e = fmaxf(zz, 0.01f * zz);      // leaky_relu (scaled)
                const float p = ((mb >> t) & 1u) ? exp2f(e) : 0.f;
                lacc += p;
                pf[t] = f2bf(p);
            }
#pragma unroll
            for (int nb = 0; nb < 4; ++nb) {
                const int f  = nb * 16 + mloc;
                const int cS = (cA & 16) | ((cA ^ (f & 15)) & 15);
                const bf16x8 bF = *(const bf16x8*)(buf + (f * 32 + cS) * 16);
                if (nb == 0) acc0 = __builtin_amdgcn_mfma_f32_16x16x32_bf16(pf, bF, acc0, 0, 0, 0);
                if (nb == 1) acc1 = __builtin_amdgcn_mfma_f32_16x16x32_bf16(pf, bF, acc1, 0, 0, 0);
                if (nb == 2) acc2 = __builtin_amdgcn_mfma_f32_16x16x32_bf16(pf, bF, acc2, 0, 0, 0);
                if (nb == 3) acc3 = __builtin_amdgcn_mfma_f32_16x16x32_bf16(pf, bF, acc3, 0, 0, 0);
            }
        }
    };

    for (int jc = 0; jc < 8; ++jc) {
        __syncthreads();   // readers of this buffer (chunk jc-2) done; DMA jc-1 drained
        // DMA chunk jc into smem[jc&1] (swizzled), 4 instr/wave
#pragma unroll
        for (int q = 0; q < 4; ++q) {
            const int p = (wave * 4 + q) * 64 + lane;       // 0..2047
            const int f  = p >> 5;
            const int cs = p & 31;
            const int c  = (cs & 16) | ((cs ^ (f & 15)) & 15);
            const char* gp = hTb + ((size_t)f * N_DIM + jc * 256) * 2 + c * 16;
            char* lp = smem[jc & 1] + (wave * 4 + q) * 1024; // + lane*16 implicit
            __builtin_amdgcn_global_load_lds(
                (const __attribute__((address_space(1))) void*)gp,
                (__attribute__((address_space(3))) void*)lp, 16, 0, 0);
        }
        if (jc > 0) compute_chunk(jc - 1, smem[(jc - 1) & 1]);
    }
    __syncthreads();       // drains DMA of chunk 7
    compute_chunk(7, smem[1]);
    __syncthreads();       // safe to reuse smem[0] as accL

    // l: sum over quads -> per-row; waves cover disjoint j -> sum in epilogue
    lacc += __shfl_xor(lacc, 16, 64);
    lacc += __shfl_xor(lacc, 32, 64);
    if (quad == 0) lred[wave][mloc] = lacc;

    // C/D layout: row r = quad*4+reg, col f = nb*16+mloc
    float* accL = (float*)smem[0];         // [8][16][64] = 32 KB
#pragma unroll
    for (int reg = 0; reg < 4; ++reg) {
        const int r = quad * 4 + reg;
        accL[(wave * 16 + r) * 64 + 0 * 16 + mloc] = acc0[reg];
        accL[(wave * 16 + r) * 64 + 1 * 16 + mloc] = acc1[reg];
        accL[(wave * 16 + r) * 64 + 2 * 16 + mloc] = acc2[reg];
        accL[(wave * 16 + r) * 64 + 3 * 16 + mloc] = acc3[reg];
    }
    __syncthreads();

    float* __restrict__ ob = out + ((size_t)b * N_DIM + i0) * C_OUT;
#pragma unroll
    for (int e = threadIdx.x; e < 32 * C_OUT; e += 512) {
        const int R = e >> 6;              // output row 0..31
        const int hf = R >> 4;             // which i-half
        const int r  = R & 15;
        float s = 0.f, ls = 0.f;
#pragma unroll
        for (int q = 0; q < 4; ++q) {
            const int w = hf * 4 + q;
            s  += accL[(w * 16 + r) * 64 + (e & 63)];
            ls += lred[w][r];
        }
        ob[e] = s / ls;
    }
}

extern "C" void kernel_launch(void* const* d_in, const int* in_sizes, int n_in,
                              void* d_out, int out_size, void* d_ws, size_t ws_size,
                              hipStream_t stream) {
    const float* inp = (const float*)d_in[0];   // [8,2048,128]
    const float* adj = (const float*)d_in[1];   // [2048,2048]
    const float* W   = (const float*)d_in[2];   // [128,64]
    const float* a   = (const float*)d_in[3];   // [128]
    float* out = (float*)d_out;                 // [8,2048,64]

    // ws layout (2.65 MB total):
    char* ws = (char*)d_ws;
    __hip_bfloat16* hT = (__hip_bfloat16*)ws;                       // 2 MB
    float* s1 = (float*)(ws + (size_t)2 * 1024 * 1024);             // 64 KB
    float* s2 = s1 + NROWS;                                         // 64 KB
    unsigned long long* mask = (unsigned long long*)(s2 + NROWS);   // 512 KB

    gat_prep<<<1024 + N_DIM, 256, 0, stream>>>(inp, W, a, adj, hT, s1, s2, mask);
    gat_attn<<<NROWS / 32, 512, 0, stream>>>(hT, s1, s2, mask, out);
}

// Round 7
// 117.003 us; speedup vs baseline: 4.4511x; 1.0176x over previous
//
#include <hip/hip_runtime.h>
#include <hip/hip_bf16.h>
#include <cstddef>
#include <cstdint>

// GAT layer: B=8, N=2048, C_IN=128, C_OUT=64, fp32 in/out.
//
// Rank-1 scores: e[b,i,j] = lrelu(s1[b,i] + s2[b,j]); mask = adj>0 | diag.
// Unnormalized softmax (shift-invariant; e bounded => exp fits fp32).
// ROUND-7 ALGEBRA: lrelu(z)=max(z,0.01z) for ALL z and exp2 is monotone =>
//   p = exp2(lrelu(z1+z2)) = max(E1*E2, F1*F2),
//   E=exp2(z), F=exp2(0.01z) precomputed PER ROW in prep (z pre-scaled log2e).
// Inner loop: 2 mul + 1 max + mask-select + bf16 pack — NO transcendental.
// l row-sum via 5th MFMA against all-ones B fragment (D[r][c]=sum_k P[r][k]).
//
// K1 (gat_prep, 3072 blocks): [0,1024) projection (h=inp@W, W in LDS, hT bf16
//     [B][C_OUT][N] via LDS transpose, E1/F1/E2/F2); [1024,3072) adj->bitmask.
// K2 (gat_attn): 32 i-rows/block, 512 thr (2 i-halves x 4 j-quarters); j in
//     256-chunks; hT chunk DMA'd to LDS (global_load_lds, double-buffered,
//     XOR-swizzled for conflict-free ds_read_b128); 16x16x32 bf16 MFMA.
//
// ws budget (round-1 lesson: stay well under 4 MB): 2M hT + 256K E/F + 512K
// mask = 2.75 MB.

#define B_DIM 8
#define N_DIM 2048
#define C_IN  128
#define C_OUT 64
#define NROWS (B_DIM * N_DIM)   // 16384
#define LOG2E 1.4426950408889634f

typedef short bf16x8 __attribute__((ext_vector_type(8)));
typedef short bf16x4 __attribute__((ext_vector_type(4)));
typedef float f32x4  __attribute__((ext_vector_type(4)));

static __device__ __forceinline__ short f2bf(float x) {
    __hip_bfloat16 b = __float2bfloat16(x);
    return *reinterpret_cast<short*>(&b);
}

// ---------------- Kernel 1: fused projection + mask-pack ----------------
__global__ __launch_bounds__(256) void gat_prep(
    const float* __restrict__ inp,   // [B,N,C_IN]
    const float* __restrict__ W,     // [C_IN,C_OUT]
    const float* __restrict__ a,     // [2*C_OUT]
    const float* __restrict__ adj,   // [N,N]
    __hip_bfloat16* __restrict__ hT, // [B][C_OUT][N] bf16
    float* __restrict__ E1, float* __restrict__ F1,   // [B*N]
    float* __restrict__ E2, float* __restrict__ F2,   // [B*N]
    unsigned long long* __restrict__ mask)  // [N][N/64], diag folded in
{
    __shared__ float Wl[C_IN * C_OUT];     // 32 KB
    __shared__ float a1l[C_OUT], a2l[C_OUT];
    __shared__ float tr[C_OUT][17];        // 16-row transpose buffer, padded

    if (blockIdx.x >= 1024) {
        // ---- mask-pack block: one adj row ----
        const int i    = blockIdx.x - 1024;
        const int wave = threadIdx.x >> 6;
        const int lane = threadIdx.x & 63;
        const float* __restrict__ arow = adj + (size_t)i * N_DIM;
#pragma unroll
        for (int it = 0; it < 8; ++it) {
            const int j = wave * 512 + it * 64 + lane;
            const bool conn = (arow[j] > 0.f) || (j == i);   // diag folded in
            const unsigned long long bm = __ballot(conn);
            if (lane == 0) mask[(size_t)i * (N_DIM / 64) + (j >> 6)] = bm;
        }
        return;
    }

    // ---- projection block: 16 rows ----
    {
        const float4* Wv = (const float4*)W;
        float4* Wd = (float4*)Wl;
        for (int t = threadIdx.x; t < C_IN * C_OUT / 4; t += 256) Wd[t] = Wv[t];
        if (threadIdx.x < C_OUT) {
            a1l[threadIdx.x] = a[threadIdx.x];
            a2l[threadIdx.x] = a[C_OUT + threadIdx.x];
        }
    }
    __syncthreads();

    const int wave = threadIdx.x >> 6;
    const int lane = threadIdx.x & 63;
    const int i0 = blockIdx.x * 16;        // 16 rows per block (never crosses batch)
    const int b  = i0 >> 11;
    const int il = i0 & (N_DIM - 1);
    const int rl = wave * 4;               // this wave's 4 rows

    const float* __restrict__ x0 = inp + (size_t)(i0 + rl) * C_IN;
    const float* __restrict__ x1 = x0 + C_IN;
    const float* __restrict__ x2 = x1 + C_IN;
    const float* __restrict__ x3 = x2 + C_IN;
    float h0 = 0.f, h1 = 0.f, h2 = 0.f, h3 = 0.f;
#pragma unroll 4
    for (int c = 0; c < C_IN; c += 4) {
        const float4 a0 = *(const float4*)(x0 + c);
        const float4 a1 = *(const float4*)(x1 + c);
        const float4 a2 = *(const float4*)(x2 + c);
        const float4 a3 = *(const float4*)(x3 + c);
#pragma unroll
        for (int cc = 0; cc < 4; ++cc) {
            const float w_ = Wl[(c + cc) * C_OUT + lane];
            const float e0 = (cc==0)?a0.x:(cc==1)?a0.y:(cc==2)?a0.z:a0.w;
            const float e1 = (cc==0)?a1.x:(cc==1)?a1.y:(cc==2)?a1.z:a1.w;
            const float e2 = (cc==0)?a2.x:(cc==1)?a2.y:(cc==2)?a2.z:a2.w;
            const float e3 = (cc==0)?a3.x:(cc==1)?a3.y:(cc==2)?a3.z:a3.w;
            h0 = fmaf(e0, w_, h0);
            h1 = fmaf(e1, w_, h1);
            h2 = fmaf(e2, w_, h2);
            h3 = fmaf(e3, w_, h3);
        }
    }
    tr[lane][rl + 0] = h0;                 // stride 17: conflict-free
    tr[lane][rl + 1] = h1;
    tr[lane][rl + 2] = h2;
    tr[lane][rl + 3] = h3;

    float hv[4] = {h0, h1, h2, h3};
#pragma unroll
    for (int k = 0; k < 4; ++k) {
        float p1 = hv[k] * a1l[lane];
        float p2 = hv[k] * a2l[lane];
#pragma unroll
        for (int off = 32; off; off >>= 1) {
            p1 += __shfl_xor(p1, off, 64);
            p2 += __shfl_xor(p2, off, 64);
        }
        if (lane == 0) {
            const float z1 = p1 * LOG2E;   // exp(x) = exp2(x*log2e)
            const float z2 = p2 * LOG2E;
            const int r = i0 + rl + k;
            E1[r] = exp2f(z1);
            F1[r] = exp2f(0.01f * z1);
            E2[r] = exp2f(z2);
            F2[r] = exp2f(0.01f * z2);
        }
    }
    __syncthreads();

    // hT[b][f][il+ro4..+4): thread t -> f = t>>2, ro4 = (t&3)*4
    const int f   = threadIdx.x >> 2;
    const int ro4 = (threadIdx.x & 3) * 4;
    bf16x4 v;
    v[0] = f2bf(tr[f][ro4 + 0]);
    v[1] = f2bf(tr[f][ro4 + 1]);
    v[2] = f2bf(tr[f][ro4 + 2]);
    v[3] = f2bf(tr[f][ro4 + 3]);
    *(bf16x4*)(hT + ((size_t)b * C_OUT + f) * N_DIM + il + ro4) = v;
}

// ---------------- Kernel 2: MFMA attention, double-buffered LDS ----------------
__global__ __launch_bounds__(512, 4) void gat_attn(
    const __hip_bfloat16* __restrict__ hT,        // [B][C_OUT][N]
    const float* __restrict__ E1, const float* __restrict__ F1,
    const float* __restrict__ E2, const float* __restrict__ F2,
    const unsigned long long* __restrict__ mask,  // [N][N/64]
    float* __restrict__ out)                      // [B,N,C_OUT]
{
    __shared__ __align__(16) char smem[2][32768]; // double buffer / epilogue accL
    __shared__ float lred[8][16];

    const int wave = threadIdx.x >> 6;     // 0..7
    const int lane = threadIdx.x & 63;
    const int half = wave >> 2;            // i-half (0/1)
    const int jq   = wave & 3;             // j-quarter within chunk
    const int tb = blockIdx.x;             // 0..511
    const int b  = tb >> 6;                // 64 row-tiles of 32 per batch
    const int i0 = (tb & 63) * 32;
    const int mloc = lane & 15;
    const int quad = lane >> 4;
    const int i_g  = i0 + half * 16 + mloc;

    const float E1v = E1[(size_t)b * N_DIM + i_g];
    const float F1v = F1[(size_t)b * N_DIM + i_g];
    const float* __restrict__ E2b = E2 + (size_t)b * N_DIM;
    const float* __restrict__ F2b = F2 + (size_t)b * N_DIM;
    const uint8_t* __restrict__ mB = (const uint8_t*)mask;   // [N][N/8] bytes (LE)
    const char* __restrict__ hTb = (const char*)(hT + (size_t)b * C_OUT * N_DIM);

    f32x4 acc0 = {0.f,0.f,0.f,0.f}, acc1 = {0.f,0.f,0.f,0.f};
    f32x4 acc2 = {0.f,0.f,0.f,0.f}, acc3 = {0.f,0.f,0.f,0.f};
    f32x4 accl = {0.f,0.f,0.f,0.f};        // l row-sums via ones-MFMA
    const bf16x8 ones = {(short)0x3F80, (short)0x3F80, (short)0x3F80, (short)0x3F80,
                         (short)0x3F80, (short)0x3F80, (short)0x3F80, (short)0x3F80};

    // compute one 256-j chunk from LDS buffer `buf`
    auto compute_chunk = [&](int jc, const char* buf) {
#pragma unroll
        for (int st = 0; st < 2; ++st) {
            const int bjl = jq * 64 + st * 32 + quad * 8;   // within-chunk j
            const int jg  = jc * 256 + bjl;
            const int cA  = bjl >> 3;                       // chunk idx 0..31
            const unsigned mb = mB[(size_t)i_g * (N_DIM / 8) + (jg >> 3)];
            const f32x4 eA = *(const f32x4*)(E2b + jg);
            const f32x4 eB = *(const f32x4*)(E2b + jg + 4);
            const f32x4 fA = *(const f32x4*)(F2b + jg);
            const f32x4 fB = *(const f32x4*)(F2b + jg + 4);
            bf16x8 pf;
#pragma unroll
            for (int t = 0; t < 8; ++t) {
                const float pe = E1v * (t < 4 ? eA[t] : eB[t - 4]);
                const float pn = F1v * (t < 4 ? fA[t] : fB[t - 4]);
                float p = fmaxf(pe, pn);                    // = exp2(lrelu(z))
                p = ((mb >> t) & 1u) ? p : 0.f;
                pf[t] = f2bf(p);
            }
            accl = __builtin_amdgcn_mfma_f32_16x16x32_bf16(pf, ones, accl, 0, 0, 0);
#pragma unroll
            for (int nb = 0; nb < 4; ++nb) {
                const int f  = nb * 16 + mloc;
                const int cS = (cA & 16) | ((cA ^ (f & 15)) & 15);
                const bf16x8 bF = *(const bf16x8*)(buf + (f * 32 + cS) * 16);
                if (nb == 0) acc0 = __builtin_amdgcn_mfma_f32_16x16x32_bf16(pf, bF, acc0, 0, 0, 0);
                if (nb == 1) acc1 = __builtin_amdgcn_mfma_f32_16x16x32_bf16(pf, bF, acc1, 0, 0, 0);
                if (nb == 2) acc2 = __builtin_amdgcn_mfma_f32_16x16x32_bf16(pf, bF, acc2, 0, 0, 0);
                if (nb == 3) acc3 = __builtin_amdgcn_mfma_f32_16x16x32_bf16(pf, bF, acc3, 0, 0, 0);
            }
        }
    };

    for (int jc = 0; jc < 8; ++jc) {
        __syncthreads();   // readers of this buffer (chunk jc-2) done; DMA jc-1 drained
        // DMA chunk jc into smem[jc&1] (swizzled), 4 instr/wave
#pragma unroll
        for (int q = 0; q < 4; ++q) {
            const int p = (wave * 4 + q) * 64 + lane;       // 0..2047
            const int f  = p >> 5;
            const int cs = p & 31;
            const int c  = (cs & 16) | ((cs ^ (f & 15)) & 15);
            const char* gp = hTb + ((size_t)f * N_DIM + jc * 256) * 2 + c * 16;
            char* lp = smem[jc & 1] + (wave * 4 + q) * 1024; // + lane*16 implicit
            __builtin_amdgcn_global_load_lds(
                (const __attribute__((address_space(1))) void*)gp,
                (__attribute__((address_space(3))) void*)lp, 16, 0, 0);
        }
        if (jc > 0) compute_chunk(jc - 1, smem[(jc - 1) & 1]);
    }
    __syncthreads();       // drains DMA of chunk 7
    compute_chunk(7, smem[1]);
    __syncthreads();       // safe to reuse smem[0] as accL

    // l: accl[reg] = row-sum for row quad*4+reg (all cols identical)
    if (mloc == 0) {
#pragma unroll
        for (int reg = 0; reg < 4; ++reg)
            lred[wave][quad * 4 + reg] = accl[reg];
    }

    // C/D layout: row r = quad*4+reg, col f = nb*16+mloc
    float* accL = (float*)smem[0];         // [8][16][64] = 32 KB
#pragma unroll
    for (int reg = 0; reg < 4; ++reg) {
        const int r = quad * 4 + reg;
        accL[(wave * 16 + r) * 64 + 0 * 16 + mloc] = acc0[reg];
        accL[(wave * 16 + r) * 64 + 1 * 16 + mloc] = acc1[reg];
        accL[(wave * 16 + r) * 64 + 2 * 16 + mloc] = acc2[reg];
        accL[(wave * 16 + r) * 64 + 3 * 16 + mloc] = acc3[reg];
    }
    __syncthreads();

    float* __restrict__ ob = out + ((size_t)b * N_DIM + i0) * C_OUT;
#pragma unroll
    for (int e = threadIdx.x; e < 32 * C_OUT; e += 512) {
        const int R = e >> 6;              // output row 0..31
        const int hf = R >> 4;             // which i-half
        const int r  = R & 15;
        float s = 0.f, ls = 0.f;
#pragma unroll
        for (int q = 0; q < 4; ++q) {
            const int w = hf * 4 + q;
            s  += accL[(w * 16 + r) * 64 + (e & 63)];
            ls += lred[w][r];
        }
        ob[e] = s / ls;
    }
}

extern "C" void kernel_launch(void* const* d_in, const int* in_sizes, int n_in,
                              void* d_out, int out_size, void* d_ws, size_t ws_size,
                              hipStream_t stream) {
    const float* inp = (const float*)d_in[0];   // [8,2048,128]
    const float* adj = (const float*)d_in[1];   // [2048,2048]
    const float* W   = (const float*)d_in[2];   // [128,64]
    const float* a   = (const float*)d_in[3];   // [128]
    float* out = (float*)d_out;                 // [8,2048,64]

    // ws layout (2.75 MB total):
    char* ws = (char*)d_ws;
    __hip_bfloat16* hT = (__hip_bfloat16*)ws;                       // 2 MB
    float* E1 = (float*)(ws + (size_t)2 * 1024 * 1024);             // 64 KB
    float* F1 = E1 + NROWS;                                         // 64 KB
    float* E2 = F1 + NROWS;                                         // 64 KB
    float* F2 = E2 + NROWS;                                         // 64 KB
    unsigned long long* mask = (unsigned long long*)(F2 + NROWS);   // 512 KB

    gat_prep<<<1024 + N_DIM, 256, 0, stream>>>(inp, W, a, adj, hT, E1, F1, E2, F2, mask);
    gat_attn<<<NROWS / 32, 512, 0, stream>>>(hT, E1, F1, E2, F2, mask, out);
}